// Round 3
// baseline (328.696 us; speedup 1.0000x reference)
//
#include <hip/hip_runtime.h>

// Problem constants
#define BATCH 2
#define NSEQ 2304       // 48*48
#define DIM 768
#define HEADS 12
#define HD 64
#define M_TOK (BATCH * NSEQ)   // 4608
#define LDSP 72                // padded LDS row stride (bf16 elems)

typedef __attribute__((ext_vector_type(8))) short bf16x8;
typedef __attribute__((ext_vector_type(4))) float f32x4;
typedef _Float16 half4 __attribute__((ext_vector_type(4)));

// softmax scale folded with log2(e): exp(x) = exp2(x * log2e)
#define QSCALE (0.125f * 1.44269504088896f)

__device__ __forceinline__ short f2bf(float f) {
    union { float f; unsigned u; } v; v.f = f;
    unsigned r = v.u + 0x7fffu + ((v.u >> 16) & 1u);
    return (short)(r >> 16);
}
__device__ __forceinline__ float bf2f(short s) {
    union { unsigned u; float f; } v; v.u = ((unsigned)(unsigned short)s) << 16;
    return v.f;
}

// ---------------- fp32 -> bf16 conversion (4 elems/thread) ----------------
__global__ void cvt_bf16_kernel(const float* __restrict__ in, short* __restrict__ out, int n4) {
    int i = blockIdx.x * 256 + threadIdx.x;
    if (i < n4) {
        float4 v = reinterpret_cast<const float4*>(in)[i];
        short4 o;
        o.x = f2bf(v.x); o.y = f2bf(v.y); o.z = f2bf(v.z); o.w = f2bf(v.w);
        reinterpret_cast<short4*>(out)[i] = o;
    }
}

// ---------------- qkv GEMM: 128x128 tile, [4608,768] x [2304,768]^T + bias ----------------
// scatters q,k -> [b,h,tok,d] bf16 ; v -> [b,h,d,tok] f16 (transposed)
__global__ __launch_bounds__(256) void gemm_qkv_kernel(
    const short* __restrict__ A,    // xb [4608,768]
    const short* __restrict__ Bt,   // wqkvb [2304,768]
    const float* __restrict__ bias, // [2304]
    short* __restrict__ qb, short* __restrict__ kbuf, _Float16* __restrict__ vtb)
{
    __shared__ __align__(16) short At[128 * LDSP];
    __shared__ __align__(16) short Bl[128 * LDSP];
    const int m0 = blockIdx.x * 128, n0 = blockIdx.y * 128;
    const int tid = threadIdx.x, lane = tid & 63, wave = tid >> 6;
    const int quad = lane >> 4, l16 = lane & 15;
    const int wm = (wave >> 1) * 64, wn = (wave & 1) * 64;
    const int r = tid >> 1, c0 = (tid & 1) * 32;
    f32x4 acc[4][4] = {};

    for (int k0 = 0; k0 < DIM; k0 += 64) {
        const uint4* ga = reinterpret_cast<const uint4*>(&A[(size_t)(m0 + r) * DIM + k0 + c0]);
        const uint4* gb = reinterpret_cast<const uint4*>(&Bt[(size_t)(n0 + r) * DIM + k0 + c0]);
        uint4 a0 = ga[0], a1 = ga[1], a2 = ga[2], a3 = ga[3];
        uint4 b0 = gb[0], b1 = gb[1], b2 = gb[2], b3 = gb[3];
        uint4* sa = reinterpret_cast<uint4*>(&At[r * LDSP + c0]);
        uint4* sb = reinterpret_cast<uint4*>(&Bl[r * LDSP + c0]);
        sa[0] = a0; sa[1] = a1; sa[2] = a2; sa[3] = a3;
        sb[0] = b0; sb[1] = b1; sb[2] = b2; sb[3] = b3;
        __syncthreads();
#pragma unroll
        for (int ks = 0; ks < 2; ++ks) {
            bf16x8 af[4], bf[4];
#pragma unroll
            for (int mt = 0; mt < 4; ++mt)
                af[mt] = *reinterpret_cast<const bf16x8*>(&At[(wm + mt * 16 + l16) * LDSP + ks * 32 + quad * 8]);
#pragma unroll
            for (int nt = 0; nt < 4; ++nt)
                bf[nt] = *reinterpret_cast<const bf16x8*>(&Bl[(wn + nt * 16 + l16) * LDSP + ks * 32 + quad * 8]);
#pragma unroll
            for (int mt = 0; mt < 4; ++mt)
#pragma unroll
                for (int nt = 0; nt < 4; ++nt)
                    acc[mt][nt] = __builtin_amdgcn_mfma_f32_16x16x32_bf16(af[mt], bf[nt], acc[mt][nt], 0, 0, 0);
        }
        __syncthreads();
    }

    const int which = (n0 + wn) / DIM;          // 0=q 1=k 2=v (wave-uniform)
    const int head = ((n0 + wn) % DIM) / HD;
    const int b = m0 / NSEQ;
    const int tokb = m0 % NSEQ + wm;
#pragma unroll
    for (int mt = 0; mt < 4; ++mt) {
#pragma unroll
        for (int nt = 0; nt < 4; ++nt) {
            const int n = n0 + wn + nt * 16 + l16;
            const int d = nt * 16 + l16;                 // < 64
            const float bi = bias[n];
            const int tok0 = tokb + mt * 16 + quad * 4;
            if (which == 2) {
                half4 hv;
                hv.x = (_Float16)(acc[mt][nt][0] + bi);
                hv.y = (_Float16)(acc[mt][nt][1] + bi);
                hv.z = (_Float16)(acc[mt][nt][2] + bi);
                hv.w = (_Float16)(acc[mt][nt][3] + bi);
                *reinterpret_cast<half4*>(&vtb[((size_t)(b * HEADS + head) * HD + d) * NSEQ + tok0]) = hv;
            } else {
                short* dst = (which == 0) ? qb : kbuf;
#pragma unroll
                for (int rg = 0; rg < 4; ++rg)
                    dst[((size_t)(b * HEADS + head) * NSEQ + tok0 + rg) * HD + d] =
                        f2bf(acc[mt][nt][rg] + bi);
            }
        }
    }
}

// ---------------- RoPE in-place on q,k [bh, tok, 64] ----------------
// q additionally pre-scaled by QSCALE (softmax scale * log2e, folded into logits)
__global__ void rope_kernel(short* __restrict__ qb, short* __restrict__ kb) {
    int idx = blockIdx.x * 256 + threadIdx.x;  // total 24*2304*32
    if (idx >= BATCH * HEADS * NSEQ * 32) return;
    const int i = idx & 31;
    const int tok = (idx >> 5) % NSEQ;
    const int bh = idx / (32 * NSEQ);
    const int y = tok / 48, x = tok % 48;
    const int pi = (i < 16) ? i : (i - 16);
    const float coord = (i < 16) ? (2.0f * (y + 0.5f) / 48.0f - 1.0f)
                                 : (2.0f * (x + 0.5f) / 48.0f - 1.0f);
    const float period = powf(100.0f, (float)pi * (1.0f / 16.0f));
    const float ang = 2.0f * 3.14159265358979323846f * coord / period;
    const float s = sinf(ang), c = cosf(ang);
    const size_t base = ((size_t)bh * NSEQ + tok) * HD;
    float q1 = bf2f(qb[base + i]), q2 = bf2f(qb[base + i + 32]);
    qb[base + i]      = f2bf((q1 * c - q2 * s) * QSCALE);
    qb[base + i + 32] = f2bf((q2 * c + q1 * s) * QSCALE);
    float k1 = bf2f(kb[base + i]), k2 = bf2f(kb[base + i + 32]);
    kb[base + i]      = f2bf(k1 * c - k2 * s);
    kb[base + i + 32] = f2bf(k2 * c + k1 * s);
}

// ---------------- flash attention: no LDS, no barriers ----------------
// grid (18, 12, 2), block 256. Each wave: 32 q-rows, streams K/V from global (L1-shared).
// S^T = K Q^T via mfma(kf, qf): C-layout of S^T == A-layout of 16x16x16 f16 MFMA,
// so P = exp2(S^T) packs straight into PV A-fragments in registers.
#define ATTN_TILE(KF, KFN, KT)                                                      \
    {                                                                               \
        const int kb0 = (KT) * 64;                                                  \
        half4 vf[4][4];                                                             \
        _Pragma("unroll") for (int nt = 0; nt < 4; ++nt)                            \
            _Pragma("unroll") for (int dt = 0; dt < 4; ++dt)                        \
                vf[nt][dt] = *reinterpret_cast<const half4*>(                       \
                    &vbase[(size_t)(dt * 16 + l16) * NSEQ + kb0 + nt * 16 + quad * 4]); \
        if ((KT) + 1 < NT) {                                                        \
            _Pragma("unroll") for (int nt = 0; nt < 4; ++nt)                        \
                _Pragma("unroll") for (int ks = 0; ks < 2; ++ks)                    \
                    KFN[nt][ks] = *reinterpret_cast<const bf16x8*>(                 \
                        &kbase[(size_t)(kb0 + 64 + nt * 16 + l16) * HD + ks * 32 + quad * 8]); \
        }                                                                           \
        f32x4 sacc[4][2] = {};                                                      \
        _Pragma("unroll") for (int ks = 0; ks < 2; ++ks)                            \
            _Pragma("unroll") for (int nt = 0; nt < 4; ++nt)                        \
                _Pragma("unroll") for (int mt = 0; mt < 2; ++mt)                    \
                    sacc[nt][mt] = __builtin_amdgcn_mfma_f32_16x16x32_bf16(         \
                        KF[nt][ks], qf[mt][ks], sacc[nt][mt], 0, 0, 0);             \
        half4 pf[2][4];                                                             \
        _Pragma("unroll") for (int mt = 0; mt < 2; ++mt)                            \
            _Pragma("unroll") for (int nt = 0; nt < 4; ++nt) {                      \
                pf[mt][nt].x = (_Float16)__builtin_amdgcn_exp2f(sacc[nt][mt][0]);   \
                pf[mt][nt].y = (_Float16)__builtin_amdgcn_exp2f(sacc[nt][mt][1]);   \
                pf[mt][nt].z = (_Float16)__builtin_amdgcn_exp2f(sacc[nt][mt][2]);   \
                pf[mt][nt].w = (_Float16)__builtin_amdgcn_exp2f(sacc[nt][mt][3]);   \
            }                                                                       \
        _Pragma("unroll") for (int mt = 0; mt < 2; ++mt)                            \
            _Pragma("unroll") for (int nt = 0; nt < 4; ++nt)                        \
                lacc[mt] = __builtin_amdgcn_mfma_f32_16x16x16f16(                   \
                    pf[mt][nt], ones, lacc[mt], 0, 0, 0);                           \
        _Pragma("unroll") for (int nt = 0; nt < 4; ++nt)                            \
            _Pragma("unroll") for (int dt = 0; dt < 4; ++dt)                        \
                _Pragma("unroll") for (int mt = 0; mt < 2; ++mt)                    \
                    oacc[mt][dt] = __builtin_amdgcn_mfma_f32_16x16x16f16(           \
                        pf[mt][nt], vf[nt][dt], oacc[mt][dt], 0, 0, 0);             \
    }

__global__ __launch_bounds__(256) void attn_kernel(
    const short* __restrict__ qb, const short* __restrict__ kb,
    const _Float16* __restrict__ vtb, short* __restrict__ ob)
{
    const int qt = blockIdx.x, h = blockIdx.y, b = blockIdx.z;
    const int bh = b * HEADS + h;
    const int tid = threadIdx.x, lane = tid & 63, wave = tid >> 6;
    const int quad = lane >> 4, l16 = lane & 15;
    const int qrow0 = qt * 128 + wave * 32;
    const short* qbase = qb + (size_t)bh * NSEQ * HD;
    const short* kbase = kb + (size_t)bh * NSEQ * HD;
    const _Float16* vbase = vtb + (size_t)bh * HD * NSEQ;

    bf16x8 qf[2][2];
#pragma unroll
    for (int mt = 0; mt < 2; ++mt)
#pragma unroll
        for (int ks = 0; ks < 2; ++ks)
            qf[mt][ks] = *reinterpret_cast<const bf16x8*>(
                &qbase[(size_t)(qrow0 + mt * 16 + l16) * HD + ks * 32 + quad * 8]);

    half4 ones;
    ones.x = ones.y = ones.z = ones.w = (_Float16)1.0f;

    f32x4 oacc[2][4] = {};
    f32x4 lacc[2] = {};

    const int NT = NSEQ / 64;   // 36 (even)
    bf16x8 kf0[4][2], kf1[4][2];
#pragma unroll
    for (int nt = 0; nt < 4; ++nt)
#pragma unroll
        for (int ks = 0; ks < 2; ++ks)
            kf0[nt][ks] = *reinterpret_cast<const bf16x8*>(
                &kbase[(size_t)(nt * 16 + l16) * HD + ks * 32 + quad * 8]);

    for (int kt = 0; kt < NT; kt += 2) {
        ATTN_TILE(kf0, kf1, kt)
        ATTN_TILE(kf1, kf0, kt + 1)
    }

    // normalize + store to o_flat [b*2304+row, h*64+d] bf16
#pragma unroll
    for (int mt = 0; mt < 2; ++mt) {
        float inv[4];
#pragma unroll
        for (int rg = 0; rg < 4; ++rg) inv[rg] = __builtin_amdgcn_rcpf(lacc[mt][rg]);
#pragma unroll
        for (int dt = 0; dt < 4; ++dt)
#pragma unroll
            for (int rg = 0; rg < 4; ++rg) {
                int row = qrow0 + mt * 16 + quad * 4 + rg;
                int col = h * HD + dt * 16 + l16;
                ob[((size_t)b * NSEQ + row) * DIM + col] = f2bf(oacc[mt][dt][rg] * inv[rg]);
            }
    }
}

// ---------------- proj GEMM: [4608,768] x [768,768]^T + bias -> fp32 out ----------------
__global__ __launch_bounds__(256) void gemm_proj_kernel(
    const short* __restrict__ A,    // ob [4608,768]
    const short* __restrict__ Bt,   // wprojb [768,768]
    const float* __restrict__ bias, // [768]
    float* __restrict__ out)
{
    __shared__ __align__(16) short At[64 * LDSP];
    __shared__ __align__(16) short Bl[64 * LDSP];
    const int m0 = blockIdx.x * 64, n0 = blockIdx.y * 64;
    const int tid = threadIdx.x, lane = tid & 63, wave = tid >> 6;
    const int quad = lane >> 4, l16 = lane & 15;
    const int wm = (wave >> 1) * 32, wn = (wave & 1) * 32;
    const int r = tid >> 2, cs = (tid & 3) * 16;
    f32x4 acc[2][2] = {};

    for (int k0 = 0; k0 < DIM; k0 += 64) {
        const uint4* ga = reinterpret_cast<const uint4*>(&A[(size_t)(m0 + r) * DIM + k0 + cs]);
        uint4* sa = reinterpret_cast<uint4*>(&At[r * LDSP + cs]);
        sa[0] = ga[0]; sa[1] = ga[1];
        const uint4* gb = reinterpret_cast<const uint4*>(&Bt[(size_t)(n0 + r) * DIM + k0 + cs]);
        uint4* sb = reinterpret_cast<uint4*>(&Bl[r * LDSP + cs]);
        sb[0] = gb[0]; sb[1] = gb[1];
        __syncthreads();
#pragma unroll
        for (int ks = 0; ks < 2; ++ks) {
            bf16x8 af[2], bf[2];
#pragma unroll
            for (int mt = 0; mt < 2; ++mt)
                af[mt] = *reinterpret_cast<const bf16x8*>(&At[(wm + mt * 16 + l16) * LDSP + ks * 32 + quad * 8]);
#pragma unroll
            for (int nt = 0; nt < 2; ++nt)
                bf[nt] = *reinterpret_cast<const bf16x8*>(&Bl[(wn + nt * 16 + l16) * LDSP + ks * 32 + quad * 8]);
#pragma unroll
            for (int mt = 0; mt < 2; ++mt)
#pragma unroll
                for (int nt = 0; nt < 2; ++nt)
                    acc[mt][nt] = __builtin_amdgcn_mfma_f32_16x16x32_bf16(af[mt], bf[nt], acc[mt][nt], 0, 0, 0);
        }
        __syncthreads();
    }

#pragma unroll
    for (int mt = 0; mt < 2; ++mt)
#pragma unroll
        for (int nt = 0; nt < 2; ++nt) {
            const int n = n0 + wn + nt * 16 + l16;
            const float bi = bias[n];
#pragma unroll
            for (int rg = 0; rg < 4; ++rg) {
                const int m = m0 + wm + mt * 16 + quad * 4 + rg;
                out[(size_t)m * DIM + n] = acc[mt][nt][rg] + bi;
            }
        }
}

extern "C" void kernel_launch(void* const* d_in, const int* in_sizes, int n_in,
                              void* d_out, int out_size, void* d_ws, size_t ws_size,
                              hipStream_t stream) {
    const float* x      = (const float*)d_in[0];
    const float* w_qkv  = (const float*)d_in[1];
    const float* b_qkv  = (const float*)d_in[2];
    const float* w_proj = (const float*)d_in[3];
    const float* b_proj = (const float*)d_in[4];
    float* out = (float*)d_out;

    short* xb     = (short*)d_ws;                       // 4608*768
    short* wqkvb  = xb + (size_t)M_TOK * DIM;           // 2304*768
    short* wprojb = wqkvb + (size_t)3 * DIM * DIM;      // 768*768
    short* qb     = wprojb + (size_t)DIM * DIM;         // 24*2304*64
    short* kb     = qb + (size_t)BATCH * HEADS * NSEQ * HD;
    short* vtb    = kb + (size_t)BATCH * HEADS * NSEQ * HD;   // f16 [b,h,d,tok]
    short* ob     = vtb + (size_t)BATCH * HEADS * NSEQ * HD;

    // converts
    cvt_bf16_kernel<<<(M_TOK * DIM / 4 + 255) / 256, 256, 0, stream>>>(x, xb, M_TOK * DIM / 4);
    cvt_bf16_kernel<<<(3 * DIM * DIM / 4 + 255) / 256, 256, 0, stream>>>(w_qkv, wqkvb, 3 * DIM * DIM / 4);
    cvt_bf16_kernel<<<(DIM * DIM / 4 + 255) / 256, 256, 0, stream>>>(w_proj, wprojb, DIM * DIM / 4);

    // qkv GEMM + scatter (128x128 tiles)
    dim3 g1(M_TOK / 128, 3 * DIM / 128);
    gemm_qkv_kernel<<<g1, 256, 0, stream>>>(xb, wqkvb, b_qkv, qb, kb, (_Float16*)vtb);

    // RoPE (+ Q prescale for exp2-domain softmax)
    int rope_n = BATCH * HEADS * NSEQ * 32;
    rope_kernel<<<(rope_n + 255) / 256, 256, 0, stream>>>(qb, kb);

    // attention (LDS-free, barrier-free)
    dim3 g2(NSEQ / 128, HEADS, BATCH);
    attn_kernel<<<g2, 256, 0, stream>>>(qb, kb, (const _Float16*)vtb, ob);

    // proj GEMM
    dim3 g3(M_TOK / 64, DIM / 64);
    gemm_proj_kernel<<<g3, 256, 0, stream>>>(ob, wprojb, b_proj, out);
}

// Round 4
// 197.640 us; speedup vs baseline: 1.6631x; 1.6631x over previous
//
#include <hip/hip_runtime.h>

// Problem constants
#define BATCH 2
#define NSEQ 2304       // 48*48
#define DIM 768
#define HEADS 12
#define HD 64
#define M_TOK (BATCH * NSEQ)   // 4608
#define LDSP 72                // padded LDS row stride (bf16 elems)
#define KP 72                  // attn LDS stride (elems) for K (bf16) and V^T (f16)

typedef __attribute__((ext_vector_type(8))) short bf16x8;
typedef __attribute__((ext_vector_type(4))) float f32x4;
typedef _Float16 half4 __attribute__((ext_vector_type(4)));

// softmax scale folded with log2(e): exp(x) = exp2(x * log2e)
#define QSCALE (0.125f * 1.44269504088896f)

__device__ __forceinline__ short f2bf(float f) {
    union { float f; unsigned u; } v; v.f = f;
    unsigned r = v.u + 0x7fffu + ((v.u >> 16) & 1u);
    return (short)(r >> 16);
}
__device__ __forceinline__ float bf2f(short s) {
    union { unsigned u; float f; } v; v.u = ((unsigned)(unsigned short)s) << 16;
    return v.f;
}

// ---------------- fp32 -> bf16 conversion (4 elems/thread) ----------------
__global__ void cvt_bf16_kernel(const float* __restrict__ in, short* __restrict__ out, int n4) {
    int i = blockIdx.x * 256 + threadIdx.x;
    if (i < n4) {
        float4 v = reinterpret_cast<const float4*>(in)[i];
        short4 o;
        o.x = f2bf(v.x); o.y = f2bf(v.y); o.z = f2bf(v.z); o.w = f2bf(v.w);
        reinterpret_cast<short4*>(out)[i] = o;
    }
}

// ---------------- qkv GEMM: 128x128 tile, [4608,768] x [2304,768]^T + bias ----------------
// scatters q,k -> [b,h,tok,d] bf16 ; v -> [b,h,d,tok] f16 (transposed)
__global__ __launch_bounds__(256) void gemm_qkv_kernel(
    const short* __restrict__ A,    // xb [4608,768]
    const short* __restrict__ Bt,   // wqkvb [2304,768]
    const float* __restrict__ bias, // [2304]
    short* __restrict__ qb, short* __restrict__ kbuf, _Float16* __restrict__ vtb)
{
    __shared__ __align__(16) short At[128 * LDSP];
    __shared__ __align__(16) short Bl[128 * LDSP];
    const int m0 = blockIdx.x * 128, n0 = blockIdx.y * 128;
    const int tid = threadIdx.x, lane = tid & 63, wave = tid >> 6;
    const int quad = lane >> 4, l16 = lane & 15;
    const int wm = (wave >> 1) * 64, wn = (wave & 1) * 64;
    const int r = tid >> 1, c0 = (tid & 1) * 32;
    f32x4 acc[4][4] = {};

    for (int k0 = 0; k0 < DIM; k0 += 64) {
        const uint4* ga = reinterpret_cast<const uint4*>(&A[(size_t)(m0 + r) * DIM + k0 + c0]);
        const uint4* gb = reinterpret_cast<const uint4*>(&Bt[(size_t)(n0 + r) * DIM + k0 + c0]);
        uint4 a0 = ga[0], a1 = ga[1], a2 = ga[2], a3 = ga[3];
        uint4 b0 = gb[0], b1 = gb[1], b2 = gb[2], b3 = gb[3];
        uint4* sa = reinterpret_cast<uint4*>(&At[r * LDSP + c0]);
        uint4* sb = reinterpret_cast<uint4*>(&Bl[r * LDSP + c0]);
        sa[0] = a0; sa[1] = a1; sa[2] = a2; sa[3] = a3;
        sb[0] = b0; sb[1] = b1; sb[2] = b2; sb[3] = b3;
        __syncthreads();
#pragma unroll
        for (int ks = 0; ks < 2; ++ks) {
            bf16x8 af[4], bf[4];
#pragma unroll
            for (int mt = 0; mt < 4; ++mt)
                af[mt] = *reinterpret_cast<const bf16x8*>(&At[(wm + mt * 16 + l16) * LDSP + ks * 32 + quad * 8]);
#pragma unroll
            for (int nt = 0; nt < 4; ++nt)
                bf[nt] = *reinterpret_cast<const bf16x8*>(&Bl[(wn + nt * 16 + l16) * LDSP + ks * 32 + quad * 8]);
#pragma unroll
            for (int mt = 0; mt < 4; ++mt)
#pragma unroll
                for (int nt = 0; nt < 4; ++nt)
                    acc[mt][nt] = __builtin_amdgcn_mfma_f32_16x16x32_bf16(af[mt], bf[nt], acc[mt][nt], 0, 0, 0);
        }
        __syncthreads();
    }

    const int which = (n0 + wn) / DIM;          // 0=q 1=k 2=v (wave-uniform)
    const int head = ((n0 + wn) % DIM) / HD;
    const int b = m0 / NSEQ;
    const int tokb = m0 % NSEQ + wm;
#pragma unroll
    for (int mt = 0; mt < 4; ++mt) {
#pragma unroll
        for (int nt = 0; nt < 4; ++nt) {
            const int n = n0 + wn + nt * 16 + l16;
            const int d = nt * 16 + l16;                 // < 64
            const float bi = bias[n];
            const int tok0 = tokb + mt * 16 + quad * 4;
            if (which == 2) {
                half4 hv;
                hv.x = (_Float16)(acc[mt][nt][0] + bi);
                hv.y = (_Float16)(acc[mt][nt][1] + bi);
                hv.z = (_Float16)(acc[mt][nt][2] + bi);
                hv.w = (_Float16)(acc[mt][nt][3] + bi);
                *reinterpret_cast<half4*>(&vtb[((size_t)(b * HEADS + head) * HD + d) * NSEQ + tok0]) = hv;
            } else {
                short* dst = (which == 0) ? qb : kbuf;
#pragma unroll
                for (int rg = 0; rg < 4; ++rg)
                    dst[((size_t)(b * HEADS + head) * NSEQ + tok0 + rg) * HD + d] =
                        f2bf(acc[mt][nt][rg] + bi);
            }
        }
    }
}

// ---------------- RoPE in-place on q,k [bh, tok, 64] ----------------
// q additionally pre-scaled by QSCALE (softmax scale * log2e, folded into logits)
__global__ void rope_kernel(short* __restrict__ qb, short* __restrict__ kb) {
    int idx = blockIdx.x * 256 + threadIdx.x;  // total 24*2304*32
    if (idx >= BATCH * HEADS * NSEQ * 32) return;
    const int i = idx & 31;
    const int tok = (idx >> 5) % NSEQ;
    const int bh = idx / (32 * NSEQ);
    const int y = tok / 48, x = tok % 48;
    const int pi = (i < 16) ? i : (i - 16);
    const float coord = (i < 16) ? (2.0f * (y + 0.5f) / 48.0f - 1.0f)
                                 : (2.0f * (x + 0.5f) / 48.0f - 1.0f);
    const float period = powf(100.0f, (float)pi * (1.0f / 16.0f));
    const float ang = 2.0f * 3.14159265358979323846f * coord / period;
    const float s = sinf(ang), c = cosf(ang);
    const size_t base = ((size_t)bh * NSEQ + tok) * HD;
    float q1 = bf2f(qb[base + i]), q2 = bf2f(qb[base + i + 32]);
    qb[base + i]      = f2bf((q1 * c - q2 * s) * QSCALE);
    qb[base + i + 32] = f2bf((q2 * c + q1 * s) * QSCALE);
    float k1 = bf2f(kb[base + i]), k2 = bf2f(kb[base + i + 32]);
    kb[base + i]      = f2bf(k1 * c - k2 * s);
    kb[base + i + 32] = f2bf(k2 * c + k1 * s);
}

// ---------------- flash attention: LDS-staged K/V, register-resident P ----------------
// grid (18, 12, 2), block 256 (4 waves x 32 q-rows).
// S^T = K Q^T via mfma(kf, qf): C-layout of S^T == A-layout of 16x16x16 f16 MFMA,
// so P = exp2(S^T) feeds PV and the ones-MFMA row-sum straight from registers.
// K/V tiles double-buffered in LDS: 1 barrier per k-tile.
__global__ __launch_bounds__(256) void attn_kernel(
    const short* __restrict__ qb, const short* __restrict__ kb,
    const _Float16* __restrict__ vtb, short* __restrict__ ob)
{
    __shared__ __align__(16) short    Kt[2][64 * KP];   // [key][d]   bf16
    __shared__ __align__(16) _Float16 Vt[2][64 * KP];   // [d][tok]   f16
    const int qt = blockIdx.x, h = blockIdx.y, b = blockIdx.z;
    const int bh = b * HEADS + h;
    const int tid = threadIdx.x, lane = tid & 63, wave = tid >> 6;
    const int quad = lane >> 4, l16 = lane & 15;
    const int qrow0 = qt * 128 + wave * 32;
    const short* qbase = qb + (size_t)bh * NSEQ * HD;
    const short* kbase = kb + (size_t)bh * NSEQ * HD;
    const _Float16* vbase = vtb + (size_t)bh * HD * NSEQ;

    // Q fragments (already scaled by QSCALE in rope)
    bf16x8 qf[2][2];
#pragma unroll
    for (int mt = 0; mt < 2; ++mt)
#pragma unroll
        for (int ks = 0; ks < 2; ++ks)
            qf[mt][ks] = *reinterpret_cast<const bf16x8*>(
                &qbase[(size_t)(qrow0 + mt * 16 + l16) * HD + ks * 32 + quad * 8]);

    half4 ones;
    ones.x = ones.y = ones.z = ones.w = (_Float16)1.0f;

    f32x4 oacc[2][4] = {};
    f32x4 lacc[2] = {};

    const int r = tid >> 2, cq = (tid & 3) * 16;   // 64 rows x 32B chunks
    // stage tile 0
    {
        const uint4* gk = reinterpret_cast<const uint4*>(&kbase[(size_t)r * HD + cq]);
        uint4 k0 = gk[0], k1 = gk[1];
        const uint4* gv = reinterpret_cast<const uint4*>(&vbase[(size_t)r * NSEQ + cq]);
        uint4 v0 = gv[0], v1 = gv[1];
        uint4* sk = reinterpret_cast<uint4*>(&Kt[0][r * KP + cq]);
        sk[0] = k0; sk[1] = k1;
        uint4* sv = reinterpret_cast<uint4*>(&Vt[0][r * KP + cq]);
        sv[0] = v0; sv[1] = v1;
    }

    int cur = 0;
    const int NT = NSEQ / 64;   // 36
    for (int kt = 0; kt < NT; ++kt) {
        uint4 k0, k1, v0, v1;
        if (kt + 1 < NT) {
            const int nb0 = (kt + 1) * 64;
            const uint4* gk = reinterpret_cast<const uint4*>(&kbase[(size_t)(nb0 + r) * HD + cq]);
            k0 = gk[0]; k1 = gk[1];
            const uint4* gv = reinterpret_cast<const uint4*>(&vbase[(size_t)r * NSEQ + nb0 + cq]);
            v0 = gv[0]; v1 = gv[1];
        }
        __syncthreads();   // buf[cur] ready; everyone done reading buf[cur^1]

        // S^T = K Q^T : C rows = keys (quad*4+rg), cols = q-rows (l16)
        f32x4 sacc[4][2] = {};
#pragma unroll
        for (int ks = 0; ks < 2; ++ks) {
#pragma unroll
            for (int nt = 0; nt < 4; ++nt) {
                bf16x8 kf = *reinterpret_cast<const bf16x8*>(
                    &Kt[cur][(nt * 16 + l16) * KP + ks * 32 + quad * 8]);
#pragma unroll
                for (int mt = 0; mt < 2; ++mt)
                    sacc[nt][mt] = __builtin_amdgcn_mfma_f32_16x16x32_bf16(
                        kf, qf[mt][ks], sacc[nt][mt], 0, 0, 0);
            }
        }

        // P = exp2(S^T): packs directly into f16 A-fragments (A[m=l16][k=quad*4+j])
        half4 pf[2][4];
#pragma unroll
        for (int mt = 0; mt < 2; ++mt)
#pragma unroll
            for (int nt = 0; nt < 4; ++nt) {
                pf[mt][nt].x = (_Float16)__builtin_amdgcn_exp2f(sacc[nt][mt][0]);
                pf[mt][nt].y = (_Float16)__builtin_amdgcn_exp2f(sacc[nt][mt][1]);
                pf[mt][nt].z = (_Float16)__builtin_amdgcn_exp2f(sacc[nt][mt][2]);
                pf[mt][nt].w = (_Float16)__builtin_amdgcn_exp2f(sacc[nt][mt][3]);
            }

        // l += P * ones (row sums, no cross-lane ops)
#pragma unroll
        for (int mt = 0; mt < 2; ++mt)
#pragma unroll
            for (int nt = 0; nt < 4; ++nt)
                lacc[mt] = __builtin_amdgcn_mfma_f32_16x16x16f16(
                    pf[mt][nt], ones, lacc[mt], 0, 0, 0);

        // O += P V : B[k=quad*4+j][n=l16] = V[key][d] from V^T LDS tile
#pragma unroll
        for (int nt = 0; nt < 4; ++nt)
#pragma unroll
            for (int dt = 0; dt < 4; ++dt) {
                half4 vf = *reinterpret_cast<const half4*>(
                    &Vt[cur][(dt * 16 + l16) * KP + nt * 16 + quad * 4]);
#pragma unroll
                for (int mt = 0; mt < 2; ++mt)
                    oacc[mt][dt] = __builtin_amdgcn_mfma_f32_16x16x16f16(
                        pf[mt][nt], vf, oacc[mt][dt], 0, 0, 0);
            }

        if (kt + 1 < NT) {   // stage next tile into the other buffer
            uint4* sk = reinterpret_cast<uint4*>(&Kt[cur ^ 1][r * KP + cq]);
            sk[0] = k0; sk[1] = k1;
            uint4* sv = reinterpret_cast<uint4*>(&Vt[cur ^ 1][r * KP + cq]);
            sv[0] = v0; sv[1] = v1;
        }
        cur ^= 1;
    }

    // normalize + store to o_flat [b*2304+row, h*64+d] bf16
#pragma unroll
    for (int mt = 0; mt < 2; ++mt) {
        float inv[4];
#pragma unroll
        for (int rg = 0; rg < 4; ++rg) inv[rg] = __builtin_amdgcn_rcpf(lacc[mt][rg]);
#pragma unroll
        for (int dt = 0; dt < 4; ++dt)
#pragma unroll
            for (int rg = 0; rg < 4; ++rg) {
                int row = qrow0 + mt * 16 + quad * 4 + rg;
                int col = h * HD + dt * 16 + l16;
                ob[((size_t)b * NSEQ + row) * DIM + col] = f2bf(oacc[mt][dt][rg] * inv[rg]);
            }
    }
}

// ---------------- proj GEMM: [4608,768] x [768,768]^T + bias -> fp32 out ----------------
__global__ __launch_bounds__(256) void gemm_proj_kernel(
    const short* __restrict__ A,    // ob [4608,768]
    const short* __restrict__ Bt,   // wprojb [768,768]
    const float* __restrict__ bias, // [768]
    float* __restrict__ out)
{
    __shared__ __align__(16) short At[64 * LDSP];
    __shared__ __align__(16) short Bl[64 * LDSP];
    const int m0 = blockIdx.x * 64, n0 = blockIdx.y * 64;
    const int tid = threadIdx.x, lane = tid & 63, wave = tid >> 6;
    const int quad = lane >> 4, l16 = lane & 15;
    const int wm = (wave >> 1) * 32, wn = (wave & 1) * 32;
    const int r = tid >> 2, cs = (tid & 3) * 16;
    f32x4 acc[2][2] = {};

    for (int k0 = 0; k0 < DIM; k0 += 64) {
        const uint4* ga = reinterpret_cast<const uint4*>(&A[(size_t)(m0 + r) * DIM + k0 + cs]);
        uint4* sa = reinterpret_cast<uint4*>(&At[r * LDSP + cs]);
        sa[0] = ga[0]; sa[1] = ga[1];
        const uint4* gb = reinterpret_cast<const uint4*>(&Bt[(size_t)(n0 + r) * DIM + k0 + cs]);
        uint4* sb = reinterpret_cast<uint4*>(&Bl[r * LDSP + cs]);
        sb[0] = gb[0]; sb[1] = gb[1];
        __syncthreads();
#pragma unroll
        for (int ks = 0; ks < 2; ++ks) {
            bf16x8 af[2], bf[2];
#pragma unroll
            for (int mt = 0; mt < 2; ++mt)
                af[mt] = *reinterpret_cast<const bf16x8*>(&At[(wm + mt * 16 + l16) * LDSP + ks * 32 + quad * 8]);
#pragma unroll
            for (int nt = 0; nt < 2; ++nt)
                bf[nt] = *reinterpret_cast<const bf16x8*>(&Bl[(wn + nt * 16 + l16) * LDSP + ks * 32 + quad * 8]);
#pragma unroll
            for (int mt = 0; mt < 2; ++mt)
#pragma unroll
                for (int nt = 0; nt < 2; ++nt)
                    acc[mt][nt] = __builtin_amdgcn_mfma_f32_16x16x32_bf16(af[mt], bf[nt], acc[mt][nt], 0, 0, 0);
        }
        __syncthreads();
    }

#pragma unroll
    for (int mt = 0; mt < 2; ++mt)
#pragma unroll
        for (int nt = 0; nt < 2; ++nt) {
            const int n = n0 + wn + nt * 16 + l16;
            const float bi = bias[n];
#pragma unroll
            for (int rg = 0; rg < 4; ++rg) {
                const int m = m0 + wm + mt * 16 + quad * 4 + rg;
                out[(size_t)m * DIM + n] = acc[mt][nt][rg] + bi;
            }
        }
}

extern "C" void kernel_launch(void* const* d_in, const int* in_sizes, int n_in,
                              void* d_out, int out_size, void* d_ws, size_t ws_size,
                              hipStream_t stream) {
    const float* x      = (const float*)d_in[0];
    const float* w_qkv  = (const float*)d_in[1];
    const float* b_qkv  = (const float*)d_in[2];
    const float* w_proj = (const float*)d_in[3];
    const float* b_proj = (const float*)d_in[4];
    float* out = (float*)d_out;

    short* xb     = (short*)d_ws;                       // 4608*768
    short* wqkvb  = xb + (size_t)M_TOK * DIM;           // 2304*768
    short* wprojb = wqkvb + (size_t)3 * DIM * DIM;      // 768*768
    short* qb     = wprojb + (size_t)DIM * DIM;         // 24*2304*64
    short* kb     = qb + (size_t)BATCH * HEADS * NSEQ * HD;
    short* vtb    = kb + (size_t)BATCH * HEADS * NSEQ * HD;   // f16 [b,h,d,tok]
    short* ob     = vtb + (size_t)BATCH * HEADS * NSEQ * HD;

    // converts
    cvt_bf16_kernel<<<(M_TOK * DIM / 4 + 255) / 256, 256, 0, stream>>>(x, xb, M_TOK * DIM / 4);
    cvt_bf16_kernel<<<(3 * DIM * DIM / 4 + 255) / 256, 256, 0, stream>>>(w_qkv, wqkvb, 3 * DIM * DIM / 4);
    cvt_bf16_kernel<<<(DIM * DIM / 4 + 255) / 256, 256, 0, stream>>>(w_proj, wprojb, DIM * DIM / 4);

    // qkv GEMM + scatter (128x128 tiles)
    dim3 g1(M_TOK / 128, 3 * DIM / 128);
    gemm_qkv_kernel<<<g1, 256, 0, stream>>>(xb, wqkvb, b_qkv, qb, kb, (_Float16*)vtb);

    // RoPE (+ Q prescale for exp2-domain softmax)
    int rope_n = BATCH * HEADS * NSEQ * 32;
    rope_kernel<<<(rope_n + 255) / 256, 256, 0, stream>>>(qb, kb);

    // attention (LDS K/V double-buffer + register-resident P)
    dim3 g2(NSEQ / 128, HEADS, BATCH);
    attn_kernel<<<g2, 256, 0, stream>>>(qb, kb, (const _Float16*)vtb, ob);

    // proj GEMM
    dim3 g3(M_TOK / 64, DIM / 64);
    gemm_proj_kernel<<<g3, 256, 0, stream>>>(ob, wprojb, b_proj, out);
}

// Round 5
// 184.902 us; speedup vs baseline: 1.7777x; 1.0689x over previous
//
#include <hip/hip_runtime.h>

// Problem constants
#define BATCH 2
#define NSEQ 2304       // 48*48
#define DIM 768
#define HEADS 12
#define HD 64
#define M_TOK (BATCH * NSEQ)   // 4608
#define LDSP 72                // padded LDS row stride (bf16 elems)
#define KP 72                  // attn LDS stride (elems) for K (bf16) and V^T (f16)
#define BH (BATCH * HEADS)     // 24
#define KT_HALF (NSEQ / 64 / 2) // 18 key-tiles per half

typedef __attribute__((ext_vector_type(8))) short bf16x8;
typedef __attribute__((ext_vector_type(8))) short short8v;
typedef __attribute__((ext_vector_type(4))) float f32x4;
typedef _Float16 half4 __attribute__((ext_vector_type(4)));
typedef _Float16 half8 __attribute__((ext_vector_type(8)));

// softmax scale folded with log2(e): exp(x) = exp2(x * log2e)
#define QSCALE (0.125f * 1.44269504088896f)
#define LOG2_100_D16 0.41524101186092029f   // log2(100)/16

__device__ __forceinline__ short f2bf(float f) {
    union { float f; unsigned u; } v; v.f = f;
    unsigned r = v.u + 0x7fffu + ((v.u >> 16) & 1u);
    return (short)(r >> 16);
}
__device__ __forceinline__ float bf2f(short s) {
    union { unsigned u; float f; } v; v.u = ((unsigned)(unsigned short)s) << 16;
    return v.f;
}

// ---------------- merged fp32 -> bf16 conversion for x, w_qkv, w_proj ----------------
#define CN1 (M_TOK * DIM / 4)        // 884736
#define CN2 (3 * DIM * DIM / 4)      // 442368
#define CN3 (DIM * DIM / 4)          // 147456
__global__ void cvt_all_kernel(const float* __restrict__ x, const float* __restrict__ wq,
                               const float* __restrict__ wp,
                               short* __restrict__ xb, short* __restrict__ wqb,
                               short* __restrict__ wpb) {
    int i = blockIdx.x * 256 + threadIdx.x;
    const float* src; short* dst; int j;
    if (i < CN1)              { src = x;  dst = xb;  j = i; }
    else if (i < CN1 + CN2)   { src = wq; dst = wqb; j = i - CN1; }
    else                      { src = wp; dst = wpb; j = i - CN1 - CN2; }
    float4 v = reinterpret_cast<const float4*>(src)[j];
    short4 o;
    o.x = f2bf(v.x); o.y = f2bf(v.y); o.z = f2bf(v.z); o.w = f2bf(v.w);
    reinterpret_cast<short4*>(dst)[j] = o;
}

// ---------------- qkv GEMM: 128x128 tile + fused bias + RoPE + QSCALE ----------------
// q,k -> [b,h,tok,d] bf16 (RoPE'd, q pre-scaled) ; v -> [b,h,d,tok] f16 (transposed)
__global__ __launch_bounds__(256) void gemm_qkv_kernel(
    const short* __restrict__ A,    // xb [4608,768]
    const short* __restrict__ Bt,   // wqkvb [2304,768]
    const float* __restrict__ bias, // [2304]
    short* __restrict__ qb, short* __restrict__ kbuf, _Float16* __restrict__ vtb)
{
    __shared__ __align__(16) short At[128 * LDSP];
    __shared__ __align__(16) short Bl[128 * LDSP];
    const int m0 = blockIdx.x * 128, n0 = blockIdx.y * 128;
    const int tid = threadIdx.x, lane = tid & 63, wave = tid >> 6;
    const int quad = lane >> 4, l16 = lane & 15;
    const int wm = (wave >> 1) * 64, wn = (wave & 1) * 64;
    const int r = tid >> 1, c0 = (tid & 1) * 32;
    f32x4 acc[4][4] = {};

    for (int k0 = 0; k0 < DIM; k0 += 64) {
        const uint4* ga = reinterpret_cast<const uint4*>(&A[(size_t)(m0 + r) * DIM + k0 + c0]);
        const uint4* gb = reinterpret_cast<const uint4*>(&Bt[(size_t)(n0 + r) * DIM + k0 + c0]);
        uint4 a0 = ga[0], a1 = ga[1], a2 = ga[2], a3 = ga[3];
        uint4 b0 = gb[0], b1 = gb[1], b2 = gb[2], b3 = gb[3];
        uint4* sa = reinterpret_cast<uint4*>(&At[r * LDSP + c0]);
        uint4* sb = reinterpret_cast<uint4*>(&Bl[r * LDSP + c0]);
        sa[0] = a0; sa[1] = a1; sa[2] = a2; sa[3] = a3;
        sb[0] = b0; sb[1] = b1; sb[2] = b2; sb[3] = b3;
        __syncthreads();
#pragma unroll
        for (int ks = 0; ks < 2; ++ks) {
            bf16x8 af[4], bf[4];
#pragma unroll
            for (int mt = 0; mt < 4; ++mt)
                af[mt] = *reinterpret_cast<const bf16x8*>(&At[(wm + mt * 16 + l16) * LDSP + ks * 32 + quad * 8]);
#pragma unroll
            for (int nt = 0; nt < 4; ++nt)
                bf[nt] = *reinterpret_cast<const bf16x8*>(&Bl[(wn + nt * 16 + l16) * LDSP + ks * 32 + quad * 8]);
#pragma unroll
            for (int mt = 0; mt < 4; ++mt)
#pragma unroll
                for (int nt = 0; nt < 4; ++nt)
                    acc[mt][nt] = __builtin_amdgcn_mfma_f32_16x16x32_bf16(af[mt], bf[nt], acc[mt][nt], 0, 0, 0);
        }
        __syncthreads();
    }

    const int which = (n0 + wn) / DIM;          // 0=q 1=k 2=v (wave-uniform)
    const int head = ((n0 + wn) % DIM) / HD;
    const int b = m0 / NSEQ;
    const int tokb = m0 % NSEQ + wm;
    if (which == 2) {
#pragma unroll
        for (int mt = 0; mt < 4; ++mt)
#pragma unroll
            for (int nt = 0; nt < 4; ++nt) {
                const int n = n0 + wn + nt * 16 + l16;
                const int d = nt * 16 + l16;
                const float bi = bias[n];
                const int tok0 = tokb + mt * 16 + quad * 4;
                half4 hv;
                hv.x = (_Float16)(acc[mt][nt][0] + bi);
                hv.y = (_Float16)(acc[mt][nt][1] + bi);
                hv.z = (_Float16)(acc[mt][nt][2] + bi);
                hv.w = (_Float16)(acc[mt][nt][3] + bi);
                *reinterpret_cast<half4*>(&vtb[((size_t)(b * HEADS + head) * HD + d) * NSEQ + tok0]) = hv;
            }
    } else {
        // fused RoPE: pairs (d, d+32) = (nt, nt+2); pi = l16; coord y for nt even pair-base, x for odd
        short* dst = (which == 0) ? qb : kbuf;
        const float qs = (which == 0) ? QSCALE : 1.0f;
        float bi[4];
#pragma unroll
        for (int nt = 0; nt < 4; ++nt) bi[nt] = bias[n0 + wn + nt * 16 + l16];
        const float invp = __builtin_amdgcn_exp2f(-(float)l16 * LOG2_100_D16); // 100^(-l16/16)
#pragma unroll
        for (int mt = 0; mt < 4; ++mt) {
#pragma unroll
            for (int rg = 0; rg < 4; ++rg) {
                const int tok = tokb + mt * 16 + quad * 4 + rg;
                const int yy = tok / 48, xx = tok - yy * 48;
                const float ry = (2.0f * (yy + 0.5f) * (1.0f / 48.0f) - 1.0f) * invp; // revolutions
                const float rx = (2.0f * (xx + 0.5f) * (1.0f / 48.0f) - 1.0f) * invp;
                const float sy = __builtin_amdgcn_sinf(ry), cy = __builtin_amdgcn_cosf(ry);
                const float sx = __builtin_amdgcn_sinf(rx), cx = __builtin_amdgcn_cosf(rx);
                const float a0 = acc[mt][0][rg] + bi[0];
                const float a1 = acc[mt][1][rg] + bi[1];
                const float a2 = acc[mt][2][rg] + bi[2];
                const float a3 = acc[mt][3][rg] + bi[3];
                short* rp = &dst[((size_t)(b * HEADS + head) * NSEQ + tok) * HD];
                rp[l16]      = f2bf((a0 * cy - a2 * sy) * qs);
                rp[32 + l16] = f2bf((a2 * cy + a0 * sy) * qs);
                rp[16 + l16] = f2bf((a1 * cx - a3 * sx) * qs);
                rp[48 + l16] = f2bf((a3 * cx + a1 * sx) * qs);
            }
        }
    }
}

// ---------------- flash attention, key-split partials ----------------
// grid (18, 2, 24): (q-tile of 128, key-half of 1152, bh). 4 waves x 32 q-rows.
// No-max softmax => O and l are pure sums => halves combine later in proj staging.
// Writes O-partial f16 [half][bh][row][d] and l-partial f32 [half][bh][row].
__global__ __launch_bounds__(256) void attn_kernel(
    const short* __restrict__ qb, const short* __restrict__ kb,
    const _Float16* __restrict__ vtb, _Float16* __restrict__ opart,
    float* __restrict__ lpart)
{
    __shared__ __align__(16) short    Kt[2][64 * KP];   // [key][d]   bf16
    __shared__ __align__(16) _Float16 Vt[2][64 * KP];   // [d][tok]   f16
    const int qt = blockIdx.x, kh = blockIdx.y, bh = blockIdx.z;
    const int tid = threadIdx.x, lane = tid & 63, wave = tid >> 6;
    const int quad = lane >> 4, l16 = lane & 15;
    const int qrow0 = qt * 128 + wave * 32;
    const short* qbase = qb + (size_t)bh * NSEQ * HD;
    const short* kbase = kb + (size_t)bh * NSEQ * HD;
    const _Float16* vbase = vtb + (size_t)bh * HD * NSEQ;

    bf16x8 qf[2][2];
#pragma unroll
    for (int mt = 0; mt < 2; ++mt)
#pragma unroll
        for (int ks = 0; ks < 2; ++ks)
            qf[mt][ks] = *reinterpret_cast<const bf16x8*>(
                &qbase[(size_t)(qrow0 + mt * 16 + l16) * HD + ks * 32 + quad * 8]);

    half4 ones;
    ones.x = ones.y = ones.z = ones.w = (_Float16)1.0f;

    f32x4 oacc[2][4] = {};
    f32x4 lacc[2] = {};

    const int r = tid >> 2, cq = (tid & 3) * 16;
    const int t0 = kh * KT_HALF;
    {
        const uint4* gk = reinterpret_cast<const uint4*>(&kbase[(size_t)(t0 * 64 + r) * HD + cq]);
        uint4 k0 = gk[0], k1 = gk[1];
        const uint4* gv = reinterpret_cast<const uint4*>(&vbase[(size_t)r * NSEQ + t0 * 64 + cq]);
        uint4 v0 = gv[0], v1 = gv[1];
        uint4* sk = reinterpret_cast<uint4*>(&Kt[0][r * KP + cq]);
        sk[0] = k0; sk[1] = k1;
        uint4* sv = reinterpret_cast<uint4*>(&Vt[0][r * KP + cq]);
        sv[0] = v0; sv[1] = v1;
    }

    int cur = 0;
    for (int kt = 0; kt < KT_HALF; ++kt) {
        uint4 k0, k1, v0, v1;
        if (kt + 1 < KT_HALF) {
            const int nb0 = (t0 + kt + 1) * 64;
            const uint4* gk = reinterpret_cast<const uint4*>(&kbase[(size_t)(nb0 + r) * HD + cq]);
            k0 = gk[0]; k1 = gk[1];
            const uint4* gv = reinterpret_cast<const uint4*>(&vbase[(size_t)r * NSEQ + nb0 + cq]);
            v0 = gv[0]; v1 = gv[1];
        }
        __syncthreads();

        // S^T = K Q^T : C rows = keys (quad*4+rg), cols = q-rows (l16)
        f32x4 sacc[4][2] = {};
#pragma unroll
        for (int ks = 0; ks < 2; ++ks) {
#pragma unroll
            for (int nt = 0; nt < 4; ++nt) {
                bf16x8 kf = *reinterpret_cast<const bf16x8*>(
                    &Kt[cur][(nt * 16 + l16) * KP + ks * 32 + quad * 8]);
#pragma unroll
                for (int mt = 0; mt < 2; ++mt)
                    sacc[nt][mt] = __builtin_amdgcn_mfma_f32_16x16x32_bf16(
                        kf, qf[mt][ks], sacc[nt][mt], 0, 0, 0);
            }
        }

        // P = exp2(S^T): packs directly into f16 A-fragments (A[m=l16][k=quad*4+j])
        half4 pf[2][4];
#pragma unroll
        for (int mt = 0; mt < 2; ++mt)
#pragma unroll
            for (int nt = 0; nt < 4; ++nt) {
                pf[mt][nt].x = (_Float16)__builtin_amdgcn_exp2f(sacc[nt][mt][0]);
                pf[mt][nt].y = (_Float16)__builtin_amdgcn_exp2f(sacc[nt][mt][1]);
                pf[mt][nt].z = (_Float16)__builtin_amdgcn_exp2f(sacc[nt][mt][2]);
                pf[mt][nt].w = (_Float16)__builtin_amdgcn_exp2f(sacc[nt][mt][3]);
            }

        // l += P * ones (row sums in C-layout, matches oacc rows)
#pragma unroll
        for (int mt = 0; mt < 2; ++mt)
#pragma unroll
            for (int nt = 0; nt < 4; ++nt)
                lacc[mt] = __builtin_amdgcn_mfma_f32_16x16x16f16(
                    pf[mt][nt], ones, lacc[mt], 0, 0, 0);

        // O += P V
#pragma unroll
        for (int nt = 0; nt < 4; ++nt)
#pragma unroll
            for (int dt = 0; dt < 4; ++dt) {
                half4 vf = *reinterpret_cast<const half4*>(
                    &Vt[cur][(dt * 16 + l16) * KP + nt * 16 + quad * 4]);
#pragma unroll
                for (int mt = 0; mt < 2; ++mt)
                    oacc[mt][dt] = __builtin_amdgcn_mfma_f32_16x16x16f16(
                        pf[mt][nt], vf, oacc[mt][dt], 0, 0, 0);
            }

        if (kt + 1 < KT_HALF) {
            uint4* sk = reinterpret_cast<uint4*>(&Kt[cur ^ 1][r * KP + cq]);
            sk[0] = k0; sk[1] = k1;
            uint4* sv = reinterpret_cast<uint4*>(&Vt[cur ^ 1][r * KP + cq]);
            sv[0] = v0; sv[1] = v1;
        }
        cur ^= 1;
    }

    // store UNNORMALIZED partials
    _Float16* ob2 = opart + (size_t)(kh * BH + bh) * NSEQ * HD;
    float* lp2 = lpart + (size_t)(kh * BH + bh) * NSEQ;
#pragma unroll
    for (int mt = 0; mt < 2; ++mt) {
#pragma unroll
        for (int dt = 0; dt < 4; ++dt)
#pragma unroll
            for (int rg = 0; rg < 4; ++rg) {
                int row = qrow0 + mt * 16 + quad * 4 + rg;
                ob2[(size_t)row * HD + dt * 16 + l16] = (_Float16)oacc[mt][dt][rg];
            }
        if (l16 == 0) {
#pragma unroll
            for (int rg = 0; rg < 4; ++rg)
                lp2[qrow0 + mt * 16 + quad * 4 + rg] = lacc[mt][rg];
        }
    }
}

// ---------------- proj GEMM with fused softmax-combine ----------------
// A-tile k-range (64 cols) == one head; staging computes (O0+O1)*rcp(l0+l1) -> bf16.
__global__ __launch_bounds__(256) void gemm_proj_kernel(
    const _Float16* __restrict__ op,  // [2][bh][row][d] f16 partials
    const float* __restrict__ lp,     // [2][bh][row] f32 partials
    const short* __restrict__ Bt,     // wprojb [768,768]
    const float* __restrict__ bias,   // [768]
    float* __restrict__ out)
{
    __shared__ __align__(16) short At[64 * LDSP];
    __shared__ __align__(16) short Bl[64 * LDSP];
    const int m0 = blockIdx.x * 64, n0 = blockIdx.y * 64;
    const int tid = threadIdx.x, lane = tid & 63, wave = tid >> 6;
    const int quad = lane >> 4, l16 = lane & 15;
    const int wm = (wave >> 1) * 32, wn = (wave & 1) * 32;
    const int r = tid >> 2, cs = (tid & 3) * 16;
    const int b = m0 / NSEQ;
    const int tok = m0 % NSEQ + r;
    f32x4 acc[2][2] = {};

    for (int k0 = 0; k0 < DIM; k0 += 64) {
        // fused combine: this k-tile is head h
        const int h = k0 >> 6;
        const size_t pb = (size_t)(b * HEADS + h) * NSEQ + tok;
        const float l0 = lp[pb], l1 = lp[(size_t)BH * NSEQ + pb];
        const float inv = __builtin_amdgcn_rcpf(l0 + l1);
        const half8* o0 = reinterpret_cast<const half8*>(&op[pb * HD + cs]);
        const half8* o1 = reinterpret_cast<const half8*>(&op[(size_t)BH * NSEQ * HD + pb * HD + cs]);
        half8 p0 = o0[0], p1 = o0[1], q0 = o1[0], q1 = o1[1];
        const uint4* gb = reinterpret_cast<const uint4*>(&Bt[(size_t)(n0 + r) * DIM + k0 + cs]);
        uint4 bw0 = gb[0], bw1 = gb[1];
        short8v s0, s1;
#pragma unroll
        for (int j = 0; j < 8; ++j) {
            s0[j] = f2bf(((float)p0[j] + (float)q0[j]) * inv);
            s1[j] = f2bf(((float)p1[j] + (float)q1[j]) * inv);
        }
        *reinterpret_cast<short8v*>(&At[r * LDSP + cs]) = s0;
        *reinterpret_cast<short8v*>(&At[r * LDSP + cs + 8]) = s1;
        uint4* sb = reinterpret_cast<uint4*>(&Bl[r * LDSP + cs]);
        sb[0] = bw0; sb[1] = bw1;
        __syncthreads();
#pragma unroll
        for (int ks = 0; ks < 2; ++ks) {
            bf16x8 af[2], bf[2];
#pragma unroll
            for (int mt = 0; mt < 2; ++mt)
                af[mt] = *reinterpret_cast<const bf16x8*>(&At[(wm + mt * 16 + l16) * LDSP + ks * 32 + quad * 8]);
#pragma unroll
            for (int nt = 0; nt < 2; ++nt)
                bf[nt] = *reinterpret_cast<const bf16x8*>(&Bl[(wn + nt * 16 + l16) * LDSP + ks * 32 + quad * 8]);
#pragma unroll
            for (int mt = 0; mt < 2; ++mt)
#pragma unroll
                for (int nt = 0; nt < 2; ++nt)
                    acc[mt][nt] = __builtin_amdgcn_mfma_f32_16x16x32_bf16(af[mt], bf[nt], acc[mt][nt], 0, 0, 0);
        }
        __syncthreads();
    }

#pragma unroll
    for (int mt = 0; mt < 2; ++mt)
#pragma unroll
        for (int nt = 0; nt < 2; ++nt) {
            const int n = n0 + wn + nt * 16 + l16;
            const float bi = bias[n];
#pragma unroll
            for (int rg = 0; rg < 4; ++rg) {
                const int m = m0 + wm + mt * 16 + quad * 4 + rg;
                out[(size_t)m * DIM + n] = acc[mt][nt][rg] + bi;
            }
        }
}

extern "C" void kernel_launch(void* const* d_in, const int* in_sizes, int n_in,
                              void* d_out, int out_size, void* d_ws, size_t ws_size,
                              hipStream_t stream) {
    const float* x      = (const float*)d_in[0];
    const float* w_qkv  = (const float*)d_in[1];
    const float* b_qkv  = (const float*)d_in[2];
    const float* w_proj = (const float*)d_in[3];
    const float* b_proj = (const float*)d_in[4];
    float* out = (float*)d_out;

    short* xb     = (short*)d_ws;                         // 4608*768
    short* wqkvb  = xb + (size_t)M_TOK * DIM;             // 2304*768
    short* wprojb = wqkvb + (size_t)3 * DIM * DIM;        // 768*768
    short* qb     = wprojb + (size_t)DIM * DIM;           // 24*2304*64 bf16
    short* kb     = qb + (size_t)BH * NSEQ * HD;
    short* vtb    = kb + (size_t)BH * NSEQ * HD;          // f16 [bh,d,tok]
    short* opart  = vtb + (size_t)BH * NSEQ * HD;         // f16 [2,bh,row,d]
    float* lpart  = (float*)(opart + (size_t)2 * BH * NSEQ * HD); // f32 [2,bh,row]

    // merged converts (1 kernel)
    cvt_all_kernel<<<(CN1 + CN2 + CN3) / 256, 256, 0, stream>>>(
        x, w_qkv, w_proj, xb, wqkvb, wprojb);

    // qkv GEMM + bias + RoPE + QSCALE + scatter
    dim3 g1(M_TOK / 128, 3 * DIM / 128);
    gemm_qkv_kernel<<<g1, 256, 0, stream>>>(xb, wqkvb, b_qkv, qb, kb, (_Float16*)vtb);

    // attention partials (key-split x2)
    dim3 g2(NSEQ / 128, 2, BH);
    attn_kernel<<<g2, 256, 0, stream>>>(qb, kb, (const _Float16*)vtb,
                                        (_Float16*)opart, lpart);

    // proj GEMM with fused combine+normalize
    dim3 g3(M_TOK / 64, DIM / 64);
    gemm_proj_kernel<<<g3, 256, 0, stream>>>((const _Float16*)opart, lpart,
                                             wprojb, b_proj, out);
}